// Round 3
// baseline (3373.327 us; speedup 1.0000x reference)
//
#include <hip/hip_runtime.h>
#include <hip/hip_bf16.h>

// Problem constants (B,S,N,F,H,E) = (4,8,4000,64,128,32000)
#define B_  4
#define S_  8
#define N_  4000
#define F_  64
#define H_  128
#define E_  32000
#define G_  (B_*S_)        // 32 graphs
#define GN_ (G_*N_)        // 128000 node rows
#define M_  (B_*N_)        // 16000 LSTM rows
#define GE_ (G_*E_)        // 1,024,000 edges total

// f32 weight scratch offsets (floats)
#define OFF_W0S 0
#define OFF_B0S 8192
#define OFF_W0D 8320
#define OFF_B0D 16512
#define OFF_W1S 16640
#define OFF_B1S 33024
#define OFF_W1D 33152
#define OFF_B1D 49536
#define OFF_WIH 49664
#define OFF_WHH 115200
#define OFF_BIH 180736
#define OFF_BHH 181248
#define OFF_WP  181760
#define OFF_BP  189952
#define WCV_TOTAL 190016

// workspace layout (float offsets)
#define WS_FLAG   0
#define WS_WCV    16
#define WS_WPACK  190464      // 131072 ushorts = 65536 floats
#define WS_DEGO   256000
#define WS_DEGI   384000
#define WS_CNTI   512000
#define WS_CNTO   640000
#define WS_RPI    768000      // 32*4001
#define WS_RPO    896032
#define WS_CURI   1024064
#define WS_CURO   1152064
#define WS_CSRI   1280064     // int2 x GE = 2,048,000 floats
#define WS_CSRO   3328064
#define WS_P      5376064     // [GN,128] f32
#define WS_Q      21760064
#define WS_HB     38144064    // [GN,128] bf16 (or f32 if ws allows)
// bf16-Hb end: 185,344,256 B ; f32-Hb end: 218,112,256 B

__device__ inline float bfu2f(unsigned short u){ union{unsigned int i; float f;} v; v.i=((unsigned int)u)<<16; return v.f; }
__device__ inline float rcpf(float x){ return __builtin_amdgcn_rcpf(x); }
__device__ inline float sigmf(float x){ return rcpf(1.0f + __expf(-x)); }
__device__ inline float tanhfast(float x){ return 1.0f - 2.0f*rcpf(1.0f + __expf(2.0f*x)); }
__device__ inline float loadf(const void* p, long i, int isf32){
    return isf32 ? ((const float*)p)[i]
                 : __bfloat162float(((const __hip_bfloat16*)p)[i]);
}
__device__ inline void stout(float* p, float v){ *p = v; }
__device__ inline void stout(__hip_bfloat16* p, float v){ *p = __float2bfloat16(v); }
__device__ inline float4 cvtbf4(ushort4 u){
    float4 f;
    f.x = __uint_as_float(((unsigned)u.x)<<16);
    f.y = __uint_as_float(((unsigned)u.y)<<16);
    f.z = __uint_as_float(((unsigned)u.z)<<16);
    f.w = __uint_as_float(((unsigned)u.w)<<16);
    return f;
}

// ---------------- dtype sniff (inputs f32 vs bf16) ----------------
__global__ void sniff_kernel(const unsigned int* __restrict__ ew, int* __restrict__ flag){
    __shared__ int s;
    if (threadIdx.x == 0) s = 0;
    __syncthreads();
    unsigned int lo = ew[threadIdx.x] & 0xFFFFu;
    if (lo > 0x3F80u) atomicOr(&s, 1);
    __syncthreads();
    if (threadIdx.x == 0) flag[0] = s;   // 1 => inputs are f32
}

// ---------------- weight conversion to f32 scratch ----------------
struct WSeg { const void* src; int base; int n; };
struct WDesc { WSeg seg[14]; };
__global__ void convert_weights(WDesc d, float* __restrict__ dst, const int* __restrict__ flag){
    int isf32 = flag[0];
    int idx = blockIdx.x*256 + threadIdx.x;
    #pragma unroll
    for (int s=0;s<14;s++){
        int off = idx - d.seg[s].base;
        if (off >= 0 && off < d.seg[s].n){
            dst[idx] = loadf(d.seg[s].src, off, isf32);
            return;
        }
    }
}

// ---------------- LSTM weight repack: wpack[((k4*8+r)*128+j)*4+c] bf16 ----------------
// r in 0..7 = {Wih_i,Wih_f,Wih_g,Wih_o,Whh_i,Whh_f,Whh_g,Whh_o} row (j + (r&3)*128)
__global__ void repack_lstm(const float* __restrict__ wcv, unsigned short* __restrict__ wpack){
    int idx = blockIdx.x*256 + threadIdx.x;        // < 131072
    int c  = idx & 3;
    int j  = (idx>>2) & 127;
    int r  = (idx>>9) & 7;
    int k4 = idx >> 12;
    int row = j + (r&3)*128;
    int k = k4*4 + c;
    float v = (r < 4) ? wcv[OFF_WIH + row*128 + k] : wcv[OFF_WHH + row*128 + k];
    __hip_bfloat16 b = __float2bfloat16(v);
    wpack[idx] = *(unsigned short*)&b;
}

// ---------------- per-graph histogram: weighted degrees + counts ----------------
__global__ __launch_bounds__(1024) void hist_kernel(
        const int* __restrict__ ei, const void* __restrict__ ew, const int* __restrict__ flag,
        float* __restrict__ deg_o, float* __restrict__ deg_i,
        int* __restrict__ cnt_in, int* __restrict__ cnt_out){
    __shared__ float wdo[N_], wdi[N_];
    __shared__ int   co[N_],  ci[N_];
    int g = blockIdx.x, tid = threadIdx.x;
    int isf32 = flag[0];
    for (int i=tid;i<N_;i+=1024){ wdo[i]=0.f; wdi[i]=0.f; co[i]=0; ci[i]=0; }
    __syncthreads();
    const int* eib = ei + g*2*E_;
    for (int e=tid;e<E_;e+=1024){
        int s = eib[e], d = eib[E_+e];
        float w = loadf(ew, (long)g*E_+e, isf32);
        atomicAdd(&wdo[s], w); atomicAdd(&wdi[d], w);
        atomicAdd(&co[s], 1);  atomicAdd(&ci[d], 1);
    }
    __syncthreads();
    for (int i=tid;i<N_;i+=1024){
        deg_o[g*N_+i]=wdo[i]; deg_i[g*N_+i]=wdi[i];
        cnt_out[g*N_+i]=co[i]; cnt_in[g*N_+i]=ci[i];
    }
}

// ---------------- exclusive scan -> row_ptr + cursors (64 blocks: 32 g x 2 dir) ----------------
__global__ __launch_bounds__(256) void scan_kernel(
        const int* __restrict__ cnt_in, const int* __restrict__ cnt_out,
        int* __restrict__ rp_in, int* __restrict__ rp_out,
        int* __restrict__ cur_in, int* __restrict__ cur_out){
    __shared__ int part[256], pref[256];
    int g = blockIdx.x & 31, dir = blockIdx.x >> 5;
    const int* cnt = (dir ? cnt_out : cnt_in) + g*N_;
    int* rp  = (dir ? rp_out  : rp_in)  + g*(N_+1);
    int* cur = (dir ? cur_out : cur_in) + g*N_;
    int tid = threadIdx.x, base = tid*16;
    int sum = 0;
    for (int i=0;i<16;i++){ int p = base+i; if (p < N_) sum += cnt[p]; }
    part[tid] = sum;
    __syncthreads();
    if (tid == 0){ int run = 0; for (int j=0;j<256;j++){ pref[j] = run; run += part[j]; } }
    __syncthreads();
    int run = pref[tid];
    for (int i=0;i<16;i++){
        int p = base+i;
        if (p < N_){ rp[p] = run; cur[p] = run; run += cnt[p]; }
    }
    if (tid == 255) rp[N_] = run;
}

// ---------------- fill CSR: nrm + scatter edge payloads ----------------
__global__ void fill_kernel(const int* __restrict__ ei, const void* __restrict__ ew,
                            const int* __restrict__ flag,
                            const float* __restrict__ deg_o, const float* __restrict__ deg_i,
                            int* __restrict__ cur_in, int* __restrict__ cur_out,
                            int2* __restrict__ csr_in, int2* __restrict__ csr_out){
    int idx = blockIdx.x*256 + threadIdx.x;
    if (idx >= GE_) return;
    int isf32 = flag[0];
    int g = idx / E_, e = idx - g*E_;
    const int* eib = ei + g*2*E_;
    int s = eib[e], d = eib[E_ + e];
    float dout = deg_o[g*N_+s], din = deg_i[g*N_+d];
    float io = dout > 0.f ? rsqrtf(fmaxf(dout, 1e-12f)) : 0.f;
    float ii = din  > 0.f ? rsqrtf(fmaxf(din , 1e-12f)) : 0.f;
    float nrm = loadf(ew, idx, isf32) * io * ii;
    int p1 = atomicAdd(&cur_in[g*N_+d], 1);
    csr_in[(long)g*E_ + p1] = make_int2(s, __float_as_int(nrm));
    int p2 = atomicAdd(&cur_out[g*N_+s], 1);
    csr_out[(long)g*E_ + p2] = make_int2(d, __float_as_int(nrm));
}

// ---------------- gather layer 0: one wave per (g,dir,node), F=64 ----------------
__global__ void gather64(const int* __restrict__ rp_in, const int* __restrict__ rp_out,
                         const int2* __restrict__ csr_in, const int2* __restrict__ csr_out,
                         const void* __restrict__ x, const int* __restrict__ flag,
                         float* __restrict__ P, float* __restrict__ Q){
    int isf32 = flag[0];
    int wid = blockIdx.x*4 + (threadIdx.x>>6);
    int lane = threadIdx.x & 63;
    int g = wid / (2*N_); int rem = wid - g*(2*N_);
    int dir = rem / N_;   int n = rem - dir*N_;
    const int*  rp  = (dir ? rp_out : rp_in) + g*(N_+1);
    const int2* csr = (dir ? csr_out : csr_in) + (long)g*E_;
    int pb = rp[n], pe = rp[n+1];
    float acc = 0.f;
    for (int p=pb; p<pe; p++){
        int2 ent = csr[p];
        float w = __int_as_float(ent.y);
        acc += w * loadf(x, ((long)(g*N_+ent.x))*64 + lane, isf32);
    }
    float* o = dir ? Q : P;
    o[((long)(g*N_+n))*64 + lane] = acc;
}

// ---------------- gather layer 1: one wave per (g,dir,node), F=128 (float2/lane) ----------------
__device__ inline float2 ld2h(const float* hb, long rowbase, int lane){
    return ((const float2*)(hb + rowbase))[lane];
}
__device__ inline float2 ld2h(const __hip_bfloat16* hb, long rowbase, int lane){
    ushort2 u = ((const ushort2*)(hb + rowbase))[lane];
    return make_float2(bfu2f(u.x), bfu2f(u.y));
}
template<typename HbT>
__global__ void gather128(const int* __restrict__ rp_in, const int* __restrict__ rp_out,
                          const int2* __restrict__ csr_in, const int2* __restrict__ csr_out,
                          const HbT* __restrict__ hb,
                          float* __restrict__ P, float* __restrict__ Q){
    int wid = blockIdx.x*4 + (threadIdx.x>>6);
    int lane = threadIdx.x & 63;
    int g = wid / (2*N_); int rem = wid - g*(2*N_);
    int dir = rem / N_;   int n = rem - dir*N_;
    const int*  rp  = (dir ? rp_out : rp_in) + g*(N_+1);
    const int2* csr = (dir ? csr_out : csr_in) + (long)g*E_;
    int pb = rp[n], pe = rp[n+1];
    float2 acc = make_float2(0.f, 0.f);
    for (int p=pb; p<pe; p++){
        int2 ent = csr[p];
        float w = __int_as_float(ent.y);
        float2 xv = ld2h(hb, ((long)(g*N_+ent.x))*128, lane);
        acc.x += w*xv.x; acc.y += w*xv.y;
    }
    float* o = dir ? Q : P;
    ((float2*)(o + ((long)(g*N_+n))*128))[lane] = acc;
}

// --------- out = 0.5*(A @ Ws^T + bs) + 0.5*(Bm @ Wd^T + bd); out stride 128 ---------
template<int K, typename OutT>
__global__ __launch_bounds__(128) void gemm_dir(
        const float* __restrict__ Afb, const float* __restrict__ Abb,
        const float* __restrict__ Ws, const float* __restrict__ bs,
        const float* __restrict__ Wd, const float* __restrict__ bd,
        OutT* __restrict__ out){
    __shared__ float4 Af[16][K/4];
    __shared__ float4 Ab[16][K/4];
    int j = threadIdx.x;
    int row0 = blockIdx.x * 16;
    const float4* Af_g = (const float4*)(Afb + (size_t)row0*K);
    const float4* Ab_g = (const float4*)(Abb + (size_t)row0*K);
    for (int t = j; t < 16*(K/4); t += 128) {
        ((float4*)Af)[t] = Af_g[t];
        ((float4*)Ab)[t] = Ab_g[t];
    }
    __syncthreads();
    float acc[16];
    #pragma unroll
    for (int r=0;r<16;r++) acc[r]=0.f;
    const float4* Wsv = (const float4*)(Ws + j*K);
    const float4* Wdv = (const float4*)(Wd + j*K);
    for (int k4=0;k4<K/4;k4++){
        float4 a = Wsv[k4];
        float4 b = Wdv[k4];
        #pragma unroll
        for (int r=0;r<16;r++){
            float4 fa = Af[r][k4];
            float4 fb = Ab[r][k4];
            acc[r] += a.x*fa.x + a.y*fa.y + a.z*fa.z + a.w*fa.w
                    + b.x*fb.x + b.y*fb.y + b.z*fb.z + b.w*fb.w;
        }
    }
    float bias = 0.5f*(bs[j] + bd[j]);
    #pragma unroll
    for (int r=0;r<16;r++) stout(out + (size_t)(row0+r)*128 + j, 0.5f*acc[r] + bias);
}

// ---------------- fused LSTM v2 (8 steps) + projection ----------------
// 128 threads (2 waves), 16 rows/block. Thread tid owns hidden unit j=tid:
// gate rows {tid, tid+128, tid+256, tid+384}; c kept in registers.
__global__ __launch_bounds__(128,3) void lstm2(
        const float* __restrict__ hsrc, const unsigned short* __restrict__ wpack,
        const float* __restrict__ wcv, const int* __restrict__ flag,
        void* __restrict__ out){
    __shared__ float xh[16*256];   // row r: [0:128) x_t, [128:256) h
    int tid = threadIdx.x;
    int m0 = blockIdx.x * 16;
    int isf32 = flag[0];
    float c[16], hreg[16];
    #pragma unroll
    for (int r=0;r<16;r++){ c[r]=0.f; xh[r*256+128+tid]=0.f; }
    float bi = wcv[OFF_BIH+tid]     + wcv[OFF_BHH+tid];
    float bf = wcv[OFF_BIH+128+tid] + wcv[OFF_BHH+128+tid];
    float bg = wcv[OFF_BIH+256+tid] + wcv[OFF_BHH+256+tid];
    float bo = wcv[OFF_BIH+384+tid] + wcv[OFF_BHH+384+tid];
    __syncthreads();
    for (int step=0; step<8; step++){
        #pragma unroll
        for (int i=0;i<4;i++){
            int idx = tid + i*128;
            int r = idx>>5, k4 = idx&31;
            float4 v = *(const float4*)(hsrc + ((size_t)((m0+r)*8+step))*128 + k4*4);
            *(float4*)(xh + r*256 + k4*4) = v;
        }
        __syncthreads();
        float ai[16], af[16], ag[16], ao[16];
        #pragma unroll
        for (int r=0;r<16;r++){ ai[r]=bi; af[r]=bf; ag[r]=bg; ao[r]=bo; }
        for (int k4=0;k4<32;k4++){
            const unsigned short* wb = wpack + (size_t)k4*4096 + tid*4;
            float4 wxi = cvtbf4(*(const ushort4*)(wb + 0*512));
            float4 wxf = cvtbf4(*(const ushort4*)(wb + 1*512));
            float4 wxg = cvtbf4(*(const ushort4*)(wb + 2*512));
            float4 wxo = cvtbf4(*(const ushort4*)(wb + 3*512));
            float4 whi = cvtbf4(*(const ushort4*)(wb + 4*512));
            float4 whf = cvtbf4(*(const ushort4*)(wb + 5*512));
            float4 whg = cvtbf4(*(const ushort4*)(wb + 6*512));
            float4 who = cvtbf4(*(const ushort4*)(wb + 7*512));
            #pragma unroll
            for (int r=0;r<16;r++){
                float4 xv = *(float4*)(xh + r*256 + k4*4);
                float4 hv = *(float4*)(xh + r*256 + 128 + k4*4);
                ai[r] += wxi.x*xv.x + wxi.y*xv.y + wxi.z*xv.z + wxi.w*xv.w
                       + whi.x*hv.x + whi.y*hv.y + whi.z*hv.z + whi.w*hv.w;
                af[r] += wxf.x*xv.x + wxf.y*xv.y + wxf.z*xv.z + wxf.w*xv.w
                       + whf.x*hv.x + whf.y*hv.y + whf.z*hv.z + whf.w*hv.w;
                ag[r] += wxg.x*xv.x + wxg.y*xv.y + wxg.z*xv.z + wxg.w*xv.w
                       + whg.x*hv.x + whg.y*hv.y + whg.z*hv.z + whg.w*hv.w;
                ao[r] += wxo.x*xv.x + wxo.y*xv.y + wxo.z*xv.z + wxo.w*xv.w
                       + who.x*hv.x + who.y*hv.y + who.z*hv.z + who.w*hv.w;
            }
        }
        #pragma unroll
        for (int r=0;r<16;r++){
            float cc = sigmf(af[r])*c[r] + sigmf(ai[r])*tanhfast(ag[r]);
            c[r] = cc;
            hreg[r] = sigmf(ao[r])*tanhfast(cc);
        }
        __syncthreads();   // all waves done reading h
        #pragma unroll
        for (int r=0;r<16;r++) xh[r*256+128+tid] = hreg[r];
    }
    __syncthreads();
    // projection: out[m0+r][q] = h_last[r] . Wp[q] + bp[q]
    int r = tid >> 3;
    int q0 = (tid & 7) * 8;
    float pacc[8];
    #pragma unroll
    for (int q=0;q<8;q++) pacc[q] = wcv[OFF_BP + q0 + q];
    for (int k4=0;k4<32;k4++){
        float4 hv = *(float4*)(xh + r*256 + 128 + k4*4);
        #pragma unroll
        for (int q=0;q<8;q++){
            float4 wv = *(const float4*)(wcv + OFF_WP + (q0+q)*128 + k4*4);
            pacc[q] += wv.x*hv.x + wv.y*hv.y + wv.z*hv.z + wv.w*hv.w;
        }
    }
    #pragma unroll
    for (int q=0;q<8;q++){
        long o = (long)(m0+r)*64 + q0 + q;
        if (isf32) ((float*)out)[o] = pacc[q];
        else       ((__hip_bfloat16*)out)[o] = __float2bfloat16(pacc[q]);
    }
}

extern "C" void kernel_launch(void* const* d_in, const int* in_sizes, int n_in,
                              void* d_out, int out_size, void* d_ws, size_t ws_size,
                              hipStream_t stream){
    const void* x_seq      = d_in[0];
    const int*  edge_index = (const int*)d_in[1];
    const void* edge_weight= d_in[2];

    float* ws    = (float*)d_ws;
    int*   flag  = (int*)(ws + WS_FLAG);
    float* wcv   = ws + WS_WCV;
    unsigned short* wpack = (unsigned short*)(ws + WS_WPACK);
    float* deg_o = ws + WS_DEGO;
    float* deg_i = ws + WS_DEGI;
    int*   cnt_i = (int*)(ws + WS_CNTI);
    int*   cnt_o = (int*)(ws + WS_CNTO);
    int*   rp_i  = (int*)(ws + WS_RPI);
    int*   rp_o  = (int*)(ws + WS_RPO);
    int*   cur_i = (int*)(ws + WS_CURI);
    int*   cur_o = (int*)(ws + WS_CURO);
    int2*  csr_i = (int2*)(ws + WS_CSRI);
    int2*  csr_o = (int2*)(ws + WS_CSRO);
    float* P     = ws + WS_P;
    float* Q     = ws + WS_Q;
    void*  Hb    = (void*)(ws + WS_HB);
    bool hb32 = ws_size >= 218112256ull;   // f32 h0 if workspace allows, else bf16

    sniff_kernel<<<1, 256, 0, stream>>>((const unsigned int*)edge_weight, flag);
    WDesc wd;
    wd.seg[0]  = { d_in[3],  OFF_W0S, 8192  };
    wd.seg[1]  = { d_in[4],  OFF_B0S, 128   };
    wd.seg[2]  = { d_in[5],  OFF_W0D, 8192  };
    wd.seg[3]  = { d_in[6],  OFF_B0D, 128   };
    wd.seg[4]  = { d_in[7],  OFF_W1S, 16384 };
    wd.seg[5]  = { d_in[8],  OFF_B1S, 128   };
    wd.seg[6]  = { d_in[9],  OFF_W1D, 16384 };
    wd.seg[7]  = { d_in[10], OFF_B1D, 128   };
    wd.seg[8]  = { d_in[11], OFF_WIH, 65536 };
    wd.seg[9]  = { d_in[12], OFF_WHH, 65536 };
    wd.seg[10] = { d_in[13], OFF_BIH, 512   };
    wd.seg[11] = { d_in[14], OFF_BHH, 512   };
    wd.seg[12] = { d_in[15], OFF_WP,  8192  };
    wd.seg[13] = { d_in[16], OFF_BP,  64    };
    convert_weights<<<(WCV_TOTAL+255)/256, 256, 0, stream>>>(wd, wcv, flag);
    repack_lstm<<<512, 256, 0, stream>>>(wcv, wpack);

    hist_kernel<<<G_, 1024, 0, stream>>>(edge_index, edge_weight, flag, deg_o, deg_i, cnt_i, cnt_o);
    scan_kernel<<<64, 256, 0, stream>>>(cnt_i, cnt_o, rp_i, rp_o, cur_i, cur_o);
    fill_kernel<<<(GE_+255)/256, 256, 0, stream>>>(edge_index, edge_weight, flag,
                                                   deg_o, deg_i, cur_i, cur_o, csr_i, csr_o);

    // layer 0: gather (F=64, compact) then GEMM -> Hb
    gather64<<<2*G_*N_/4, 256, 0, stream>>>(rp_i, rp_o, csr_i, csr_o, x_seq, flag, P, Q);
    if (hb32){
        gemm_dir<64,float><<<GN_/16, 128, 0, stream>>>(P, Q,
            wcv+OFF_W0S, wcv+OFF_B0S, wcv+OFF_W0D, wcv+OFF_B0D, (float*)Hb);
        gather128<float><<<2*G_*N_/4, 256, 0, stream>>>(rp_i, rp_o, csr_i, csr_o, (const float*)Hb, P, Q);
    } else {
        gemm_dir<64,__hip_bfloat16><<<GN_/16, 128, 0, stream>>>(P, Q,
            wcv+OFF_W0S, wcv+OFF_B0S, wcv+OFF_W0D, wcv+OFF_B0D, (__hip_bfloat16*)Hb);
        gather128<__hip_bfloat16><<<2*G_*N_/4, 256, 0, stream>>>(rp_i, rp_o, csr_i, csr_o, (const __hip_bfloat16*)Hb, P, Q);
    }
    // layer 1 GEMM: (P,Q) -> P in-place (tile staged to LDS before writes)
    gemm_dir<128,float><<<GN_/16, 128, 0, stream>>>(P, Q,
        wcv+OFF_W1S, wcv+OFF_B1S, wcv+OFF_W1D, wcv+OFF_B1D, P);

    // fused LSTM (8 steps) + projection -> out
    lstm2<<<M_/16, 128, 0, stream>>>(P, wpack, wcv, flag, d_out);
}

// Round 4
// 1762.302 us; speedup vs baseline: 1.9142x; 1.9142x over previous
//
#include <hip/hip_runtime.h>
#include <hip/hip_bf16.h>

// Problem constants (B,S,N,F,H,E) = (4,8,4000,64,128,32000)
#define B_  4
#define S_  8
#define N_  4000
#define F_  64
#define H_  128
#define E_  32000
#define G_  (B_*S_)        // 32 graphs
#define GN_ (G_*N_)        // 128000 node rows
#define M_  (B_*N_)        // 16000 LSTM rows
#define GE_ (G_*E_)        // 1,024,000 edges total

// f32 weight scratch offsets (floats)
#define OFF_W0S 0
#define OFF_B0S 8192
#define OFF_W0D 8320
#define OFF_B0D 16512
#define OFF_W1S 16640
#define OFF_B1S 33024
#define OFF_W1D 33152
#define OFF_B1D 49536
#define OFF_WIH 49664
#define OFF_WHH 115200
#define OFF_BIH 180736
#define OFF_BHH 181248
#define OFF_WP  181760
#define OFF_BP  189952
#define WCV_TOTAL 190016

// workspace layout (float offsets)
#define WS_FLAG   0
#define WS_WCV    16
#define WS_WPACK  190464      // 131072 ushorts = 65536 floats
#define WS_DEGO   256000
#define WS_DEGI   384000
#define WS_CNTI   512000
#define WS_CNTO   640000
#define WS_RPI    768000      // 32*4001
#define WS_RPO    896032
#define WS_CURI   1024064
#define WS_CURO   1152064
#define WS_CSRI   1280064     // int2 x GE = 2,048,000 floats
#define WS_CSRO   3328064
#define WS_P      5376064     // [GN,128] f32
#define WS_Q      21760064
#define WS_HB     38144064    // [GN,128] bf16 (or f32 if ws allows)
// bf16-Hb end: 185,344,256 B ; f32-Hb end: 218,112,256 B

__device__ inline float bfu2f(unsigned short u){ union{unsigned int i; float f;} v; v.i=((unsigned int)u)<<16; return v.f; }
__device__ inline float rcpf(float x){ return __builtin_amdgcn_rcpf(x); }
__device__ inline float sigmf(float x){ return rcpf(1.0f + __expf(-x)); }
__device__ inline float tanhfast(float x){ return 1.0f - 2.0f*rcpf(1.0f + __expf(2.0f*x)); }
__device__ inline float loadf(const void* p, long i, int isf32){
    return isf32 ? ((const float*)p)[i]
                 : __bfloat162float(((const __hip_bfloat16*)p)[i]);
}
__device__ inline void stout(float* p, float v){ *p = v; }
__device__ inline void stout(__hip_bfloat16* p, float v){ *p = __float2bfloat16(v); }
__device__ inline float4 cvtbf4(ushort4 u){
    float4 f;
    f.x = __uint_as_float(((unsigned)u.x)<<16);
    f.y = __uint_as_float(((unsigned)u.y)<<16);
    f.z = __uint_as_float(((unsigned)u.z)<<16);
    f.w = __uint_as_float(((unsigned)u.w)<<16);
    return f;
}

// ---------------- dtype sniff (inputs f32 vs bf16) ----------------
__global__ void sniff_kernel(const unsigned int* __restrict__ ew, int* __restrict__ flag){
    __shared__ int s;
    if (threadIdx.x == 0) s = 0;
    __syncthreads();
    unsigned int lo = ew[threadIdx.x] & 0xFFFFu;
    if (lo > 0x3F80u) atomicOr(&s, 1);
    __syncthreads();
    if (threadIdx.x == 0) flag[0] = s;   // 1 => inputs are f32
}

// ---------------- weight conversion to f32 scratch ----------------
struct WSeg { const void* src; int base; int n; };
struct WDesc { WSeg seg[14]; };
__global__ void convert_weights(WDesc d, float* __restrict__ dst, const int* __restrict__ flag){
    int isf32 = flag[0];
    int idx = blockIdx.x*256 + threadIdx.x;
    #pragma unroll
    for (int s=0;s<14;s++){
        int off = idx - d.seg[s].base;
        if (off >= 0 && off < d.seg[s].n){
            dst[idx] = loadf(d.seg[s].src, off, isf32);
            return;
        }
    }
}

// ---------------- LSTM weight repack: wpack[((k4*8+r)*128+j)*4+c] bf16 ----------------
// r in 0..7 = {Wih_i,Wih_f,Wih_g,Wih_o,Whh_i,Whh_f,Whh_g,Whh_o} row (j + (r&3)*128)
__global__ void repack_lstm(const float* __restrict__ wcv, unsigned short* __restrict__ wpack){
    int idx = blockIdx.x*256 + threadIdx.x;        // < 131072
    int c  = idx & 3;
    int j  = (idx>>2) & 127;
    int r  = (idx>>9) & 7;
    int k4 = idx >> 12;
    int row = j + (r&3)*128;
    int k = k4*4 + c;
    float v = (r < 4) ? wcv[OFF_WIH + row*128 + k] : wcv[OFF_WHH + row*128 + k];
    __hip_bfloat16 b = __float2bfloat16(v);
    wpack[idx] = *(unsigned short*)&b;
}

// ---------------- per-graph histogram: weighted degrees + counts ----------------
__global__ __launch_bounds__(1024) void hist_kernel(
        const int* __restrict__ ei, const void* __restrict__ ew, const int* __restrict__ flag,
        float* __restrict__ deg_o, float* __restrict__ deg_i,
        int* __restrict__ cnt_in, int* __restrict__ cnt_out){
    __shared__ float wdo[N_], wdi[N_];
    __shared__ int   co[N_],  ci[N_];
    int g = blockIdx.x, tid = threadIdx.x;
    int isf32 = flag[0];
    for (int i=tid;i<N_;i+=1024){ wdo[i]=0.f; wdi[i]=0.f; co[i]=0; ci[i]=0; }
    __syncthreads();
    const int* eib = ei + g*2*E_;
    for (int e=tid;e<E_;e+=1024){
        int s = eib[e], d = eib[E_+e];
        float w = loadf(ew, (long)g*E_+e, isf32);
        atomicAdd(&wdo[s], w); atomicAdd(&wdi[d], w);
        atomicAdd(&co[s], 1);  atomicAdd(&ci[d], 1);
    }
    __syncthreads();
    for (int i=tid;i<N_;i+=1024){
        deg_o[g*N_+i]=wdo[i]; deg_i[g*N_+i]=wdi[i];
        cnt_out[g*N_+i]=co[i]; cnt_in[g*N_+i]=ci[i];
    }
}

// ---------------- exclusive scan -> row_ptr + cursors (64 blocks: 32 g x 2 dir) ----------------
__global__ __launch_bounds__(256) void scan_kernel(
        const int* __restrict__ cnt_in, const int* __restrict__ cnt_out,
        int* __restrict__ rp_in, int* __restrict__ rp_out,
        int* __restrict__ cur_in, int* __restrict__ cur_out){
    __shared__ int part[256], pref[256];
    int g = blockIdx.x & 31, dir = blockIdx.x >> 5;
    const int* cnt = (dir ? cnt_out : cnt_in) + g*N_;
    int* rp  = (dir ? rp_out  : rp_in)  + g*(N_+1);
    int* cur = (dir ? cur_out : cur_in) + g*N_;
    int tid = threadIdx.x, base = tid*16;
    int sum = 0;
    for (int i=0;i<16;i++){ int p = base+i; if (p < N_) sum += cnt[p]; }
    part[tid] = sum;
    __syncthreads();
    if (tid == 0){ int run = 0; for (int j=0;j<256;j++){ pref[j] = run; run += part[j]; } }
    __syncthreads();
    int run = pref[tid];
    for (int i=0;i<16;i++){
        int p = base+i;
        if (p < N_){ rp[p] = run; cur[p] = run; run += cnt[p]; }
    }
    if (tid == 255) rp[N_] = run;
}

// ---------------- fill CSR: nrm + scatter edge payloads ----------------
__global__ void fill_kernel(const int* __restrict__ ei, const void* __restrict__ ew,
                            const int* __restrict__ flag,
                            const float* __restrict__ deg_o, const float* __restrict__ deg_i,
                            int* __restrict__ cur_in, int* __restrict__ cur_out,
                            int2* __restrict__ csr_in, int2* __restrict__ csr_out){
    int idx = blockIdx.x*256 + threadIdx.x;
    if (idx >= GE_) return;
    int isf32 = flag[0];
    int g = idx / E_, e = idx - g*E_;
    const int* eib = ei + g*2*E_;
    int s = eib[e], d = eib[E_ + e];
    float dout = deg_o[g*N_+s], din = deg_i[g*N_+d];
    float io = dout > 0.f ? rsqrtf(fmaxf(dout, 1e-12f)) : 0.f;
    float ii = din  > 0.f ? rsqrtf(fmaxf(din , 1e-12f)) : 0.f;
    float nrm = loadf(ew, idx, isf32) * io * ii;
    int p1 = atomicAdd(&cur_in[g*N_+d], 1);
    csr_in[(long)g*E_ + p1] = make_int2(s, __float_as_int(nrm));
    int p2 = atomicAdd(&cur_out[g*N_+s], 1);
    csr_out[(long)g*E_ + p2] = make_int2(d, __float_as_int(nrm));
}

// ---------------- gather layer 0: one wave per (g,dir,node), F=64 ----------------
__global__ void gather64(const int* __restrict__ rp_in, const int* __restrict__ rp_out,
                         const int2* __restrict__ csr_in, const int2* __restrict__ csr_out,
                         const void* __restrict__ x, const int* __restrict__ flag,
                         float* __restrict__ P, float* __restrict__ Q){
    int isf32 = flag[0];
    int wid = blockIdx.x*4 + (threadIdx.x>>6);
    int lane = threadIdx.x & 63;
    int g = wid / (2*N_); int rem = wid - g*(2*N_);
    int dir = rem / N_;   int n = rem - dir*N_;
    const int*  rp  = (dir ? rp_out : rp_in) + g*(N_+1);
    const int2* csr = (dir ? csr_out : csr_in) + (long)g*E_;
    int pb = rp[n], pe = rp[n+1];
    float acc = 0.f;
    for (int p=pb; p<pe; p++){
        int2 ent = csr[p];
        float w = __int_as_float(ent.y);
        acc += w * loadf(x, ((long)(g*N_+ent.x))*64 + lane, isf32);
    }
    float* o = dir ? Q : P;
    o[((long)(g*N_+n))*64 + lane] = acc;
}

// ---------------- gather layer 1: one wave per (g,dir,node), F=128 (float2/lane) ----------------
__device__ inline float2 ld2h(const float* hb, long rowbase, int lane){
    return ((const float2*)(hb + rowbase))[lane];
}
__device__ inline float2 ld2h(const __hip_bfloat16* hb, long rowbase, int lane){
    ushort2 u = ((const ushort2*)(hb + rowbase))[lane];
    return make_float2(bfu2f(u.x), bfu2f(u.y));
}
template<typename HbT>
__global__ void gather128(const int* __restrict__ rp_in, const int* __restrict__ rp_out,
                          const int2* __restrict__ csr_in, const int2* __restrict__ csr_out,
                          const HbT* __restrict__ hb,
                          float* __restrict__ P, float* __restrict__ Q){
    int wid = blockIdx.x*4 + (threadIdx.x>>6);
    int lane = threadIdx.x & 63;
    int g = wid / (2*N_); int rem = wid - g*(2*N_);
    int dir = rem / N_;   int n = rem - dir*N_;
    const int*  rp  = (dir ? rp_out : rp_in) + g*(N_+1);
    const int2* csr = (dir ? csr_out : csr_in) + (long)g*E_;
    int pb = rp[n], pe = rp[n+1];
    float2 acc = make_float2(0.f, 0.f);
    for (int p=pb; p<pe; p++){
        int2 ent = csr[p];
        float w = __int_as_float(ent.y);
        float2 xv = ld2h(hb, ((long)(g*N_+ent.x))*128, lane);
        acc.x += w*xv.x; acc.y += w*xv.y;
    }
    float* o = dir ? Q : P;
    ((float2*)(o + ((long)(g*N_+n))*128))[lane] = acc;
}

// --------- out = 0.5*(A @ Ws^T + bs) + 0.5*(Bm @ Wd^T + bd); out stride 128 ---------
template<int K, typename OutT>
__global__ __launch_bounds__(128) void gemm_dir(
        const float* __restrict__ Afb, const float* __restrict__ Abb,
        const float* __restrict__ Ws, const float* __restrict__ bs,
        const float* __restrict__ Wd, const float* __restrict__ bd,
        OutT* __restrict__ out){
    __shared__ float4 Af[16][K/4];
    __shared__ float4 Ab[16][K/4];
    int j = threadIdx.x;
    int row0 = blockIdx.x * 16;
    const float4* Af_g = (const float4*)(Afb + (size_t)row0*K);
    const float4* Ab_g = (const float4*)(Abb + (size_t)row0*K);
    for (int t = j; t < 16*(K/4); t += 128) {
        ((float4*)Af)[t] = Af_g[t];
        ((float4*)Ab)[t] = Ab_g[t];
    }
    __syncthreads();
    float acc[16];
    #pragma unroll
    for (int r=0;r<16;r++) acc[r]=0.f;
    const float4* Wsv = (const float4*)(Ws + j*K);
    const float4* Wdv = (const float4*)(Wd + j*K);
    for (int k4=0;k4<K/4;k4++){
        float4 a = Wsv[k4];
        float4 b = Wdv[k4];
        #pragma unroll
        for (int r=0;r<16;r++){
            float4 fa = Af[r][k4];
            float4 fb = Ab[r][k4];
            acc[r] += a.x*fa.x + a.y*fa.y + a.z*fa.z + a.w*fa.w
                    + b.x*fb.x + b.y*fb.y + b.z*fb.z + b.w*fb.w;
        }
    }
    float bias = 0.5f*(bs[j] + bd[j]);
    #pragma unroll
    for (int r=0;r<16;r++) stout(out + (size_t)(row0+r)*128 + j, 0.5f*acc[r] + bias);
}

// ---------------- fused LSTM v3 (8 steps) + projection ----------------
// 256 threads (4 waves), 16 rows/block. thread = (half, j): half=tid>>7 picks
// rows [half*8, half*8+8); j=tid&127 is the hidden unit. 8 rows x 4 gates = 32
// accumulators/thread -> no spill (the v2 128-thread/64-acc layout spilled:
// VGPR=84 vs ~130 needed, WRITE_SIZE blew up to 7.8GB of scratch traffic).
__global__ __launch_bounds__(256) void lstm3(
        const float* __restrict__ hsrc, const unsigned short* __restrict__ wpack,
        const float* __restrict__ wcv, const int* __restrict__ flag,
        void* __restrict__ out){
    __shared__ float xh[16*256];   // row r: [0:128) x_t, [128:256) h
    int tid = threadIdx.x;
    int j   = tid & 127;
    int half= tid >> 7;
    int r0  = half*8;
    int m0  = blockIdx.x * 16;
    int isf32 = flag[0];
    float c[8];
    #pragma unroll
    for (int r=0;r<8;r++) c[r]=0.f;
    for (int t=tid;t<16*128;t+=256) xh[(t>>7)*256+128+(t&127)] = 0.f;
    float bi = wcv[OFF_BIH+j]     + wcv[OFF_BHH+j];
    float bf = wcv[OFF_BIH+128+j] + wcv[OFF_BHH+128+j];
    float bg = wcv[OFF_BIH+256+j] + wcv[OFF_BHH+256+j];
    float bo = wcv[OFF_BIH+384+j] + wcv[OFF_BHH+384+j];
    __syncthreads();
    for (int step=0; step<8; step++){
        #pragma unroll
        for (int i=0;i<2;i++){
            int idx = tid + i*256;
            int r = idx>>5, k4 = idx&31;
            float4 v = *(const float4*)(hsrc + ((size_t)((m0+r)*8+step))*128 + k4*4);
            *(float4*)(xh + r*256 + k4*4) = v;
        }
        __syncthreads();
        float ai[8], af[8], ag[8], ao[8];
        #pragma unroll
        for (int r=0;r<8;r++){ ai[r]=bi; af[r]=bf; ag[r]=bg; ao[r]=bo; }
        for (int k4=0;k4<32;k4++){
            const unsigned short* wb = wpack + (size_t)k4*4096 + j*4;
            float4 wxi = cvtbf4(*(const ushort4*)(wb + 0*512));
            float4 wxf = cvtbf4(*(const ushort4*)(wb + 1*512));
            float4 wxg = cvtbf4(*(const ushort4*)(wb + 2*512));
            float4 wxo = cvtbf4(*(const ushort4*)(wb + 3*512));
            float4 whi = cvtbf4(*(const ushort4*)(wb + 4*512));
            float4 whf = cvtbf4(*(const ushort4*)(wb + 5*512));
            float4 whg = cvtbf4(*(const ushort4*)(wb + 6*512));
            float4 who = cvtbf4(*(const ushort4*)(wb + 7*512));
            #pragma unroll
            for (int r=0;r<8;r++){
                float4 xv = *(float4*)(xh + (r0+r)*256 + k4*4);
                float4 hv = *(float4*)(xh + (r0+r)*256 + 128 + k4*4);
                ai[r] += wxi.x*xv.x + wxi.y*xv.y + wxi.z*xv.z + wxi.w*xv.w
                       + whi.x*hv.x + whi.y*hv.y + whi.z*hv.z + whi.w*hv.w;
                af[r] += wxf.x*xv.x + wxf.y*xv.y + wxf.z*xv.z + wxf.w*xv.w
                       + whf.x*hv.x + whf.y*hv.y + whf.z*hv.z + whf.w*hv.w;
                ag[r] += wxg.x*xv.x + wxg.y*xv.y + wxg.z*xv.z + wxg.w*xv.w
                       + whg.x*hv.x + whg.y*hv.y + whg.z*hv.z + whg.w*hv.w;
                ao[r] += wxo.x*xv.x + wxo.y*xv.y + wxo.z*xv.z + wxo.w*xv.w
                       + who.x*hv.x + who.y*hv.y + who.z*hv.z + who.w*hv.w;
            }
        }
        float hreg[8];
        #pragma unroll
        for (int r=0;r<8;r++){
            float cc = sigmf(af[r])*c[r] + sigmf(ai[r])*tanhfast(ag[r]);
            c[r] = cc;
            hreg[r] = sigmf(ao[r])*tanhfast(cc);
        }
        __syncthreads();   // all waves done reading x,h of this step
        #pragma unroll
        for (int r=0;r<8;r++) xh[(r0+r)*256+128+j] = hreg[r];
        // next-iter x-write targets [0:128) region; h region safe. One sync per
        // step boundary (top of loop) orders h/x writes vs reads.
    }
    __syncthreads();
    // projection: out[m0+r][q] = h_last[r] . Wp[q] + bp[q]
    int r = tid >> 4;
    int q0 = (tid & 15) * 4;
    float pacc[4];
    #pragma unroll
    for (int q=0;q<4;q++) pacc[q] = wcv[OFF_BP + q0 + q];
    for (int k4=0;k4<32;k4++){
        float4 hv = *(float4*)(xh + r*256 + 128 + k4*4);
        #pragma unroll
        for (int q=0;q<4;q++){
            float4 wv = *(const float4*)(wcv + OFF_WP + (q0+q)*128 + k4*4);
            pacc[q] += wv.x*hv.x + wv.y*hv.y + wv.z*hv.z + wv.w*hv.w;
        }
    }
    #pragma unroll
    for (int q=0;q<4;q++){
        long o = (long)(m0+r)*64 + q0 + q;
        if (isf32) ((float*)out)[o] = pacc[q];
        else       ((__hip_bfloat16*)out)[o] = __float2bfloat16(pacc[q]);
    }
}

extern "C" void kernel_launch(void* const* d_in, const int* in_sizes, int n_in,
                              void* d_out, int out_size, void* d_ws, size_t ws_size,
                              hipStream_t stream){
    const void* x_seq      = d_in[0];
    const int*  edge_index = (const int*)d_in[1];
    const void* edge_weight= d_in[2];

    float* ws    = (float*)d_ws;
    int*   flag  = (int*)(ws + WS_FLAG);
    float* wcv   = ws + WS_WCV;
    unsigned short* wpack = (unsigned short*)(ws + WS_WPACK);
    float* deg_o = ws + WS_DEGO;
    float* deg_i = ws + WS_DEGI;
    int*   cnt_i = (int*)(ws + WS_CNTI);
    int*   cnt_o = (int*)(ws + WS_CNTO);
    int*   rp_i  = (int*)(ws + WS_RPI);
    int*   rp_o  = (int*)(ws + WS_RPO);
    int*   cur_i = (int*)(ws + WS_CURI);
    int*   cur_o = (int*)(ws + WS_CURO);
    int2*  csr_i = (int2*)(ws + WS_CSRI);
    int2*  csr_o = (int2*)(ws + WS_CSRO);
    float* P     = ws + WS_P;
    float* Q     = ws + WS_Q;
    void*  Hb    = (void*)(ws + WS_HB);
    bool hb32 = ws_size >= 218112256ull;   // f32 h0 if workspace allows, else bf16

    sniff_kernel<<<1, 256, 0, stream>>>((const unsigned int*)edge_weight, flag);
    WDesc wd;
    wd.seg[0]  = { d_in[3],  OFF_W0S, 8192  };
    wd.seg[1]  = { d_in[4],  OFF_B0S, 128   };
    wd.seg[2]  = { d_in[5],  OFF_W0D, 8192  };
    wd.seg[3]  = { d_in[6],  OFF_B0D, 128   };
    wd.seg[4]  = { d_in[7],  OFF_W1S, 16384 };
    wd.seg[5]  = { d_in[8],  OFF_B1S, 128   };
    wd.seg[6]  = { d_in[9],  OFF_W1D, 16384 };
    wd.seg[7]  = { d_in[10], OFF_B1D, 128   };
    wd.seg[8]  = { d_in[11], OFF_WIH, 65536 };
    wd.seg[9]  = { d_in[12], OFF_WHH, 65536 };
    wd.seg[10] = { d_in[13], OFF_BIH, 512   };
    wd.seg[11] = { d_in[14], OFF_BHH, 512   };
    wd.seg[12] = { d_in[15], OFF_WP,  8192  };
    wd.seg[13] = { d_in[16], OFF_BP,  64    };
    convert_weights<<<(WCV_TOTAL+255)/256, 256, 0, stream>>>(wd, wcv, flag);
    repack_lstm<<<512, 256, 0, stream>>>(wcv, wpack);

    hist_kernel<<<G_, 1024, 0, stream>>>(edge_index, edge_weight, flag, deg_o, deg_i, cnt_i, cnt_o);
    scan_kernel<<<64, 256, 0, stream>>>(cnt_i, cnt_o, rp_i, rp_o, cur_i, cur_o);
    fill_kernel<<<(GE_+255)/256, 256, 0, stream>>>(edge_index, edge_weight, flag,
                                                   deg_o, deg_i, cur_i, cur_o, csr_i, csr_o);

    // layer 0: gather (F=64, compact) then GEMM -> Hb
    gather64<<<2*G_*N_/4, 256, 0, stream>>>(rp_i, rp_o, csr_i, csr_o, x_seq, flag, P, Q);
    if (hb32){
        gemm_dir<64,float><<<GN_/16, 128, 0, stream>>>(P, Q,
            wcv+OFF_W0S, wcv+OFF_B0S, wcv+OFF_W0D, wcv+OFF_B0D, (float*)Hb);
        gather128<float><<<2*G_*N_/4, 256, 0, stream>>>(rp_i, rp_o, csr_i, csr_o, (const float*)Hb, P, Q);
    } else {
        gemm_dir<64,__hip_bfloat16><<<GN_/16, 128, 0, stream>>>(P, Q,
            wcv+OFF_W0S, wcv+OFF_B0S, wcv+OFF_W0D, wcv+OFF_B0D, (__hip_bfloat16*)Hb);
        gather128<__hip_bfloat16><<<2*G_*N_/4, 256, 0, stream>>>(rp_i, rp_o, csr_i, csr_o, (const __hip_bfloat16*)Hb, P, Q);
    }
    // layer 1 GEMM: (P,Q) -> P in-place (each block reads only rows it writes)
    gemm_dir<128,float><<<GN_/16, 128, 0, stream>>>(P, Q,
        wcv+OFF_W1S, wcv+OFF_B1S, wcv+OFF_W1D, wcv+OFF_B1D, P);

    // fused LSTM (8 steps) + projection -> out
    lstm3<<<M_/16, 256, 0, stream>>>(P, wpack, wcv, flag, d_out);
}